// Round 6
// baseline (1896.086 us; speedup 1.0000x reference)
//
#include <hip/hip_runtime.h>

#define NN      100000
#define NUSERS  50000
#define NE      1250000
#define DIM     64
#define BN_EPS  1e-5f
#define TILE    128
#define NT      782          // ceil(NN/128)
#define SEGCAP  384          // per-(tile,b8) capacity: mean 200, sd 14 -> 13 sigma
#define NSEG    (NT * 8)

typedef __attribute__((ext_vector_type(8))) short s16x8;
typedef __attribute__((ext_vector_type(4))) float f32x4;

__device__ __forceinline__ short f2b(float f) {  // fp32 -> bf16 RNE
    unsigned u = __builtin_bit_cast(unsigned, f);
    u = (u + 0x7fffu + ((u >> 16) & 1u)) >> 16;
    return (short)u;
}
__device__ __forceinline__ float b2f(unsigned short s) {
    unsigned u = ((unsigned)s) << 16;
    return __builtin_bit_cast(float, u);
}

// ---------------------------------------------------------------------------
// Single-pass edge binning into per-(dst-tile, blockIdx&7) segments.
// b8 = blockIdx&7 tracks XCD (heuristic; correctness independent): cursor and
// segment-tail atomics stay XCD-local. Record = (d&127)<<17 | s (24 bits).
__global__ __launch_bounds__(256) void bin_tiles(const int* __restrict__ ei,
                                                 unsigned* __restrict__ subbins,
                                                 int* __restrict__ segcnt) {
    int b8 = blockIdx.x & 7;
    int stride = gridDim.x * 256;
    for (int e = blockIdx.x * 256 + threadIdx.x; e < NE; e += stride) {
        int s = __builtin_nontemporal_load(&ei[e]);
        int d = __builtin_nontemporal_load(&ei[NE + e]);
        int seg = (d >> 7) * 8 + b8;
        int pos = atomicAdd(&segcnt[seg], 1);
        if (pos < SEGCAP)
            subbins[(size_t)seg * SEGCAP + pos] = ((unsigned)(d & 127) << 17) | (unsigned)s;
    }
}

// ---------------------------------------------------------------------------
// Per-tile degree count from the 8 segments -> dinv. One block per tile.
__global__ __launch_bounds__(256) void tile_dinv(const unsigned* __restrict__ subbins,
                                                 const int* __restrict__ segcnt,
                                                 float* __restrict__ dinv) {
    __shared__ int cnt[TILE];
    int tile = blockIdx.x;
    if (threadIdx.x < TILE) cnt[threadIdx.x] = 0;
    __syncthreads();
    for (int b8 = 0; b8 < 8; ++b8) {
        int seg = tile * 8 + b8;
        int c = segcnt[seg];
        if (c > SEGCAP) c = SEGCAP;
        const unsigned* base = subbins + (size_t)seg * SEGCAP;
        for (int i = threadIdx.x; i < c; i += 256)
            atomicAdd(&cnt[base[i] >> 17], 1);
    }
    __syncthreads();
    int v = tile * TILE + threadIdx.x;
    if (threadIdx.x < TILE && v < NN)
        dinv[v] = rsqrtf((float)cnt[threadIdx.x] + 1.0f);
}

// ---------------------------------------------------------------------------
// c0[l][j] = sum_k bs[l][k] * Ws[l+1][j][k]   (bias-fold constants, layers 1,2)
__global__ __launch_bounds__(128) void c0_kernel(const float* __restrict__ Ws,
                                                 const float* __restrict__ bs,
                                                 float* __restrict__ c0) {
    int t = threadIdx.x;
    if (t < 128) {
        int l = t >> 6, j = t & 63;
        const float* Wl = Ws + (size_t)(l + 1) * 4096;
        const float* bl = bs + l * 64;
        float s = 0.0f;
        for (int k = 0; k < 64; ++k) s += bl[k] * Wl[j * 64 + k];
        c0[t] = s;
    }
}

// ---------------------------------------------------------------------------
// bf16 MFMA transform: Gb = bf16(scale * (A @ W^T) + dv*c0)  (unchanged)
template <int L0>
__global__ __launch_bounds__(256) void gemm_mfma(const void* __restrict__ Xin,
                                                 const float* __restrict__ W,
                                                 const float* __restrict__ dinv,
                                                 const float* __restrict__ c0,
                                                 unsigned short* __restrict__ Gb) {
    int lane = threadIdx.x & 63;
    int n16 = lane & 15, quad = lane >> 4;

    s16x8 bfrag[4][2];
#pragma unroll
    for (int t = 0; t < 4; ++t)
#pragma unroll
        for (int c = 0; c < 2; ++c) {
            const float4* wp = (const float4*)(W + (t * 16 + n16) * 64 + c * 32 + quad * 8);
            float4 w0 = wp[0], w1 = wp[1];
            s16x8 f;
            f[0] = f2b(w0.x); f[1] = f2b(w0.y); f[2] = f2b(w0.z); f[3] = f2b(w0.w);
            f[4] = f2b(w1.x); f[5] = f2b(w1.y); f[6] = f2b(w1.z); f[7] = f2b(w1.w);
            bfrag[t][c] = f;
        }

    int wid = (blockIdx.x * blockDim.x + threadIdx.x) >> 6;
    int nw  = (gridDim.x * blockDim.x) >> 6;
    for (int tile = wid; tile < NN / 16; tile += nw) {
        int r0 = tile * 16;
        int m  = r0 + n16;
        s16x8 a[2];
#pragma unroll
        for (int c = 0; c < 2; ++c) {
            if (L0) {
                const float4* xp = (const float4*)((const float*)Xin + (size_t)m * 64 + c * 32 + quad * 8);
                float4 x0 = xp[0], x1 = xp[1];
                s16x8 f;
                f[0] = f2b(x0.x); f[1] = f2b(x0.y); f[2] = f2b(x0.z); f[3] = f2b(x0.w);
                f[4] = f2b(x1.x); f[5] = f2b(x1.y); f[6] = f2b(x1.z); f[7] = f2b(x1.w);
                a[c] = f;
            } else {
                a[c] = *(const s16x8*)((const unsigned short*)Xin + (size_t)m * 64 + c * 32 + quad * 8);
            }
        }
        f32x4 acc[4] = {{0,0,0,0},{0,0,0,0},{0,0,0,0},{0,0,0,0}};
#pragma unroll
        for (int c = 0; c < 2; ++c)
#pragma unroll
            for (int t = 0; t < 4; ++t)
                acc[t] = __builtin_amdgcn_mfma_f32_16x16x32_bf16(a[c], bfrag[t][c], acc[t], 0, 0, 0);

        float dvr[4];
#pragma unroll
        for (int r = 0; r < 4; ++r) dvr[r] = dinv[r0 + quad * 4 + r];
#pragma unroll
        for (int t = 0; t < 4; ++t) {
            float cc = L0 ? 0.0f : c0[t * 16 + n16];
#pragma unroll
            for (int r = 0; r < 4; ++r) {
                float dv = dvr[r];
                float g  = L0 ? dv * acc[t][r] : dv * dv * acc[t][r] + dv * cc;
                Gb[(size_t)(r0 + quad * 4 + r) * 64 + t * 16 + n16] = (unsigned short)f2b(g);
            }
        }
    }
}

// ---------------------------------------------------------------------------
// LDS-accumulator gather: one block per 128-node dst tile. acc initialized
// with the tile's own Gb rows (self-loop); 8 segments streamed, 8 edges in
// flight per wave; per edge one coalesced 128 B row load + one ds_add_f32/lane
// (banks = lane%32, 2-way alias = free). No global atomics, no CSR.
__global__ __launch_bounds__(256) void gather_lds(const unsigned* __restrict__ subbins,
                                                  const int* __restrict__ segcnt,
                                                  const unsigned short* __restrict__ Gb,
                                                  unsigned short* __restrict__ ACCb) {
    __shared__ float acc[TILE * 64];  // 32 KB
    int tile = blockIdx.x;
    int lane = threadIdx.x & 63;
    int wave = threadIdx.x >> 6;
    int v0 = tile * TILE;

    for (int r = wave; r < TILE; r += 4) {
        int v = v0 + r;
        acc[r * 64 + lane] = (v < NN) ? b2f(Gb[(size_t)v * 64 + lane]) : 0.0f;
    }
    __syncthreads();

    for (int b8 = wave; b8 < 8; b8 += 4) {  // waves 0..3 each own 2 segments
        int seg = tile * 8 + b8;
        int c = segcnt[seg];
        if (c > SEGCAP) c = SEGCAP;
        const unsigned* base = subbins + (size_t)seg * SEGCAP;
        int i = 0;
        for (; i + 8 <= c; i += 8) {
            unsigned rec[8];
            float val[8];
            int dr[8];
#pragma unroll
            for (int u = 0; u < 8; ++u) rec[u] = base[i + u];
#pragma unroll
            for (int u = 0; u < 8; ++u) {
                int s = rec[u] & 0x1FFFF;
                dr[u] = rec[u] >> 17;
                val[u] = b2f(Gb[(size_t)s * 64 + lane]);  // 8 rows in flight
            }
#pragma unroll
            for (int u = 0; u < 8; ++u)
                atomicAdd(&acc[dr[u] * 64 + lane], val[u]);
        }
        for (; i < c; ++i) {
            unsigned rec = base[i];
            int s = rec & 0x1FFFF;
            int d = rec >> 17;
            atomicAdd(&acc[d * 64 + lane], b2f(Gb[(size_t)s * 64 + lane]));
        }
    }
    __syncthreads();

    for (int r = wave; r < TILE; r += 4) {
        int v = v0 + r;
        if (v < NN)
            ACCb[(size_t)v * 64 + lane] = (unsigned short)f2b(acc[r * 64 + lane]);
    }
}

// ---------------------------------------------------------------------------
__global__ __launch_bounds__(256) void bn_stats(const unsigned short* __restrict__ ACCb,
                                                const float* __restrict__ dinv,
                                                const float* __restrict__ blast,
                                                float* __restrict__ sums) {
    int j = threadIdx.x & 63;
    float b = blast[j];
    int wid = (blockIdx.x * blockDim.x + threadIdx.x) >> 6;
    int nw  = (gridDim.x * blockDim.x) >> 6;
    float s = 0.0f, s2 = 0.0f;
    for (int v = wid; v < NN; v += nw) {
        float y = dinv[v] * b2f(ACCb[(size_t)v * 64 + j]) + b;
        s += y;
        s2 += y * y;
    }
    __shared__ float ls[256], ls2[256];
    ls[threadIdx.x] = s;
    ls2[threadIdx.x] = s2;
    __syncthreads();
    if (threadIdx.x < 64) {
        s  = ls[threadIdx.x] + ls[threadIdx.x + 64] + ls[threadIdx.x + 128] + ls[threadIdx.x + 192];
        s2 = ls2[threadIdx.x] + ls2[threadIdx.x + 64] + ls2[threadIdx.x + 128] + ls2[threadIdx.x + 192];
        atomicAdd(&sums[j], s);
        atomicAdd(&sums[64 + j], s2);
    }
}

__global__ __launch_bounds__(256) void bn_apply(const unsigned short* __restrict__ ACCb,
                                                const float* __restrict__ dinv,
                                                const float* __restrict__ blast,
                                                const float* __restrict__ sums,
                                                const float* __restrict__ gamma,
                                                const float* __restrict__ beta,
                                                float* __restrict__ out) {
    const float invN = 1.0f / (float)NN;
    int stride = gridDim.x * blockDim.x;
    for (int i = blockIdx.x * blockDim.x + threadIdx.x; i < NN * 64; i += stride) {
        int j = i & 63;
        int v = i >> 6;
        float mean = sums[j] * invN;
        float var  = sums[64 + j] * invN - mean * mean;
        float y = dinv[v] * b2f(ACCb[i]) + blast[j];
        out[i] = (y - mean) * rsqrtf(var + BN_EPS) * gamma[j] + beta[j];
    }
}

// ---------------------------------------------------------------------------
extern "C" void kernel_launch(void* const* d_in, const int* in_sizes, int n_in,
                              void* d_out, int out_size, void* d_ws, size_t ws_size,
                              hipStream_t stream) {
    const float* x     = (const float*)d_in[0];
    const int*   ei    = (const int*)d_in[1];
    const float* Ws    = (const float*)d_in[2];
    const float* bs    = (const float*)d_in[3];
    const float* gamma = (const float*)d_in[4];
    const float* beta  = (const float*)d_in[5];
    float* out = (float*)d_out;

    char* ws = (char*)d_ws;
    size_t off = 0;
    unsigned short* ACCb = (unsigned short*)(ws + off); off += (size_t)NN * 64 * 2;
    unsigned short* Gb   = (unsigned short*)(ws + off); off += (size_t)NN * 64 * 2;
    float*    dinv    = (float*)(ws + off);    off += (size_t)NN * 4;
    float*    sums    = (float*)(ws + off);    off += 128 * 4;
    float*    c0      = (float*)(ws + off);    off += 128 * 4;
    int*      segcnt  = (int*)(ws + off);      off += (size_t)NSEG * 4;
    unsigned* subbins = (unsigned*)(ws + off); off += (size_t)NSEG * SEGCAP * 4;

    hipMemsetAsync(segcnt, 0, NSEG * sizeof(int), stream);
    hipMemsetAsync(sums, 0, 128 * sizeof(float), stream);

    // --- edge binning (single pass) + per-tile degree/dinv ---
    bin_tiles<<<2560, 256, 0, stream>>>(ei, subbins, segcnt);
    tile_dinv<<<NT, 256, 0, stream>>>(subbins, segcnt, dinv);
    c0_kernel<<<1, 128, 0, stream>>>(Ws, bs, c0);

    // --- 3 GCN layers: MFMA transform, then LDS-accumulator gather ---
    gemm_mfma<1><<<1563, 256, 0, stream>>>(x, Ws, dinv, nullptr, Gb);
    gather_lds<<<NT, 256, 0, stream>>>(subbins, segcnt, Gb, ACCb);
    for (int l = 1; l < 3; ++l) {
        gemm_mfma<0><<<1563, 256, 0, stream>>>(ACCb, Ws + (size_t)l * 4096, dinv,
                                               c0 + (l - 1) * 64, Gb);
        gather_lds<<<NT, 256, 0, stream>>>(subbins, segcnt, Gb, ACCb);
    }

    // --- BatchNorm over nodes ---
    bn_stats<<<2048, 256, 0, stream>>>(ACCb, dinv, bs + 128, sums);
    bn_apply<<<2048, 256, 0, stream>>>(ACCb, dinv, bs + 128, sums, gamma, beta, out);
}

// Round 7
// 413.135 us; speedup vs baseline: 4.5895x; 4.5895x over previous
//
#include <hip/hip_runtime.h>

#define NN      100000
#define NUSERS  50000
#define NE      1250000
#define DIM     64
#define BN_EPS  1e-5f
#define NBUCK   16
#define NCHUNK  160     // blocks per bucket (grid 2560)
#define SLOT    40      // fixed CSR slots per node (max expected degree ~30)

typedef __attribute__((ext_vector_type(8))) short s16x8;
typedef __attribute__((ext_vector_type(4))) float f32x4;

__device__ __forceinline__ short f2b(float f) {  // fp32 -> bf16 RNE
    unsigned u = __builtin_bit_cast(unsigned, f);
    u = (u + 0x7fffu + ((u >> 16) & 1u)) >> 16;
    return (short)u;
}
__device__ __forceinline__ float b2f(unsigned short s) {
    unsigned u = ((unsigned)s) << 16;
    return __builtin_bit_cast(float, u);
}
__device__ __forceinline__ int bucket_of(int d) {  // floor(d/6250), exact for d<100000
    return (int)(((unsigned long long)(unsigned)d * 687195ull) >> 32);
}

// ---------------------------------------------------------------------------
// Slot-CSR placement, 16-bucket XCD-partitioned (proven R5 structure):
// csr[d*SLOT + cursor[d]++] = s. cursor doubles as the degree count.
__global__ __launch_bounds__(256) void place_part(const int* __restrict__ ei,
                                                  int* __restrict__ cursor,
                                                  int* __restrict__ csr_src) {
    __shared__ int Qd[4][128];
    __shared__ int Qs[4][128];
    int lane = threadIdx.x & 63, wave = threadIdx.x >> 6;
    int B = blockIdx.x & (NBUCK - 1);
    int gw = (blockIdx.x >> 4) * 4 + wave;
    const int NW  = NCHUNK * 4;
    const int per = (NE + NW - 1) / NW;
    int e0 = gw * per;
    int e1 = e0 + per; if (e1 > NE) e1 = NE;
    int qn = 0;
    for (int e = e0 + lane; e - lane < e1; e += 64) {
        bool keep = false; int d = 0, s = 0;
        if (e < e1) {
            d = __builtin_nontemporal_load(&ei[NE + e]);
            keep = (bucket_of(d) == B);
            if (keep) s = __builtin_nontemporal_load(&ei[e]);
        }
        unsigned long long m = __ballot(keep);
        if (keep) {
            int rank = __popcll(m & ((1ull << lane) - 1ull));
            Qd[wave][qn + rank] = d;
            Qs[wave][qn + rank] = s;
        }
        qn += __popcll(m);
        if (qn >= 64) {
            int dd = Qd[wave][lane];
            int ss = Qs[wave][lane];
            int pos = atomicAdd(&cursor[dd], 1);
            if (pos < SLOT) __builtin_nontemporal_store(ss, &csr_src[dd * SLOT + pos]);
            qn -= 64;
            int mvd = (lane < qn) ? Qd[wave][64 + lane] : 0;
            int mvs = (lane < qn) ? Qs[wave][64 + lane] : 0;
            if (lane < qn) { Qd[wave][lane] = mvd; Qs[wave][lane] = mvs; }
        }
    }
    if (lane < qn) {
        int dd = Qd[wave][lane];
        int pos = atomicAdd(&cursor[dd], 1);
        if (pos < SLOT) __builtin_nontemporal_store(Qs[wave][lane], &csr_src[dd * SLOT + pos]);
    }
}

// dinv[v] = rsqrt(deg[v] + 1)   (+1 = self-loop); cursor holds true degree
__global__ __launch_bounds__(256) void dinv_kernel(const int* __restrict__ cursor,
                                                   float* __restrict__ dinv) {
    int v = blockIdx.x * blockDim.x + threadIdx.x;
    if (v < NN) dinv[v] = rsqrtf((float)cursor[v] + 1.0f);
}

// ---------------------------------------------------------------------------
// c0[l][j] = sum_k bs[l][k] * Ws[l+1][j][k]   (bias-fold constants, layers 1,2)
__global__ __launch_bounds__(128) void c0_kernel(const float* __restrict__ Ws,
                                                 const float* __restrict__ bs,
                                                 float* __restrict__ c0) {
    int t = threadIdx.x;
    if (t < 128) {
        int l = t >> 6, j = t & 63;
        const float* Wl = Ws + (size_t)(l + 1) * 4096;
        const float* bl = bs + l * 64;
        float s = 0.0f;
        for (int k = 0; k < 64; ++k) s += bl[k] * Wl[j * 64 + k];
        c0[t] = s;
    }
}

// ---------------------------------------------------------------------------
// bf16 MFMA transform: Gb = bf16(scale * (A @ W^T) + dv*c0)  (unchanged)
template <int L0>
__global__ __launch_bounds__(256) void gemm_mfma(const void* __restrict__ Xin,
                                                 const float* __restrict__ W,
                                                 const float* __restrict__ dinv,
                                                 const float* __restrict__ c0,
                                                 unsigned short* __restrict__ Gb) {
    int lane = threadIdx.x & 63;
    int n16 = lane & 15, quad = lane >> 4;

    s16x8 bfrag[4][2];
#pragma unroll
    for (int t = 0; t < 4; ++t)
#pragma unroll
        for (int c = 0; c < 2; ++c) {
            const float4* wp = (const float4*)(W + (t * 16 + n16) * 64 + c * 32 + quad * 8);
            float4 w0 = wp[0], w1 = wp[1];
            s16x8 f;
            f[0] = f2b(w0.x); f[1] = f2b(w0.y); f[2] = f2b(w0.z); f[3] = f2b(w0.w);
            f[4] = f2b(w1.x); f[5] = f2b(w1.y); f[6] = f2b(w1.z); f[7] = f2b(w1.w);
            bfrag[t][c] = f;
        }

    int wid = (blockIdx.x * blockDim.x + threadIdx.x) >> 6;
    int nw  = (gridDim.x * blockDim.x) >> 6;
    for (int tile = wid; tile < NN / 16; tile += nw) {
        int r0 = tile * 16;
        int m  = r0 + n16;
        s16x8 a[2];
#pragma unroll
        for (int c = 0; c < 2; ++c) {
            if (L0) {
                const float4* xp = (const float4*)((const float*)Xin + (size_t)m * 64 + c * 32 + quad * 8);
                float4 x0 = xp[0], x1 = xp[1];
                s16x8 f;
                f[0] = f2b(x0.x); f[1] = f2b(x0.y); f[2] = f2b(x0.z); f[3] = f2b(x0.w);
                f[4] = f2b(x1.x); f[5] = f2b(x1.y); f[6] = f2b(x1.z); f[7] = f2b(x1.w);
                a[c] = f;
            } else {
                a[c] = *(const s16x8*)((const unsigned short*)Xin + (size_t)m * 64 + c * 32 + quad * 8);
            }
        }
        f32x4 acc[4] = {{0,0,0,0},{0,0,0,0},{0,0,0,0},{0,0,0,0}};
#pragma unroll
        for (int c = 0; c < 2; ++c)
#pragma unroll
            for (int t = 0; t < 4; ++t)
                acc[t] = __builtin_amdgcn_mfma_f32_16x16x32_bf16(a[c], bfrag[t][c], acc[t], 0, 0, 0);

        float dvr[4];
#pragma unroll
        for (int r = 0; r < 4; ++r) dvr[r] = dinv[r0 + quad * 4 + r];
#pragma unroll
        for (int t = 0; t < 4; ++t) {
            float cc = L0 ? 0.0f : c0[t * 16 + n16];
#pragma unroll
            for (int r = 0; r < 4; ++r) {
                float dv = dvr[r];
                float g  = L0 ? dv * acc[t][r] : dv * dv * acc[t][r] + dv * cc;
                Gb[(size_t)(r0 + quad * 4 + r) * 64 + t * 16 + n16] = (unsigned short)f2b(g);
            }
        }
    }
}

// ---------------------------------------------------------------------------
// Gather over slot-CSR, 4 neighbors per wave-instruction: lane = 16*g + c;
// group g loads the 8B chunk (cols 4c..4c+3) of neighbor slot. deg <= SLOT < 64
// so a single 64-wide window covers every row.
__global__ __launch_bounds__(256) void gather_b(const int* __restrict__ cursor,
                                                const int* __restrict__ csr_src,
                                                const unsigned short* __restrict__ Gb,
                                                unsigned short* __restrict__ ACCb) {
    int lane = threadIdx.x & 63;
    int c = lane & 15, g = lane >> 4;
    int wid  = (blockIdx.x * blockDim.x + threadIdx.x) >> 6;
    int nw   = (gridDim.x * blockDim.x) >> 6;
    for (int v = wid; v < NN; v += nw) {
        int n = cursor[v];
        if (n > SLOT) n = SLOT;
        // self-loop: group 0 only
        float ax, ay, az, aw;
        {
            ushort4 sv = *(const ushort4*)(Gb + (size_t)v * 64 + c * 4);
            float m0 = (g == 0) ? 1.0f : 0.0f;
            ax = m0 * b2f(sv.x); ay = m0 * b2f(sv.y);
            az = m0 * b2f(sv.z); aw = m0 * b2f(sv.w);
        }
        int myidx = (lane < n) ? csr_src[v * SLOT + lane] : 0;
        for (int t = 0; t < n; t += 16) {
            ushort4 val[4];
            float msk[4];
#pragma unroll
            for (int u = 0; u < 4; ++u) {
                int nb = t + u * 4 + g;              // neighbor slot in window
                int s = __shfl(myidx, nb & 63, 64);
                bool ok = nb < n;
                msk[u] = ok ? 1.0f : 0.0f;
                const ushort4* p = (const ushort4*)(Gb + (size_t)(ok ? s : v) * 64 + c * 4);
                val[u] = *p;                          // 4 independent loads in flight
            }
#pragma unroll
            for (int u = 0; u < 4; ++u) {
                ax = fmaf(msk[u], b2f(val[u].x), ax);
                ay = fmaf(msk[u], b2f(val[u].y), ay);
                az = fmaf(msk[u], b2f(val[u].z), az);
                aw = fmaf(msk[u], b2f(val[u].w), aw);
            }
        }
        // combine the 4 group partials
#pragma unroll
        for (int off = 16; off < 64; off <<= 1) {
            ax += __shfl_xor(ax, off, 64);
            ay += __shfl_xor(ay, off, 64);
            az += __shfl_xor(az, off, 64);
            aw += __shfl_xor(aw, off, 64);
        }
        if (g == 0) {
            ushort4 o;
            o.x = (unsigned short)f2b(ax); o.y = (unsigned short)f2b(ay);
            o.z = (unsigned short)f2b(az); o.w = (unsigned short)f2b(aw);
            *(ushort4*)(ACCb + (size_t)v * 64 + c * 4) = o;
        }
    }
}

// ---------------------------------------------------------------------------
__global__ __launch_bounds__(256) void bn_stats(const unsigned short* __restrict__ ACCb,
                                                const float* __restrict__ dinv,
                                                const float* __restrict__ blast,
                                                float* __restrict__ sums) {
    int j = threadIdx.x & 63;
    float b = blast[j];
    int wid = (blockIdx.x * blockDim.x + threadIdx.x) >> 6;
    int nw  = (gridDim.x * blockDim.x) >> 6;
    float s = 0.0f, s2 = 0.0f;
    for (int v = wid; v < NN; v += nw) {
        float y = dinv[v] * b2f(ACCb[(size_t)v * 64 + j]) + b;
        s += y;
        s2 += y * y;
    }
    __shared__ float ls[256], ls2[256];
    ls[threadIdx.x] = s;
    ls2[threadIdx.x] = s2;
    __syncthreads();
    if (threadIdx.x < 64) {
        s  = ls[threadIdx.x] + ls[threadIdx.x + 64] + ls[threadIdx.x + 128] + ls[threadIdx.x + 192];
        s2 = ls2[threadIdx.x] + ls2[threadIdx.x + 64] + ls2[threadIdx.x + 128] + ls2[threadIdx.x + 192];
        atomicAdd(&sums[j], s);
        atomicAdd(&sums[64 + j], s2);
    }
}

__global__ __launch_bounds__(256) void bn_apply(const unsigned short* __restrict__ ACCb,
                                                const float* __restrict__ dinv,
                                                const float* __restrict__ blast,
                                                const float* __restrict__ sums,
                                                const float* __restrict__ gamma,
                                                const float* __restrict__ beta,
                                                float* __restrict__ out) {
    const float invN = 1.0f / (float)NN;
    int stride = gridDim.x * blockDim.x;
    for (int i = blockIdx.x * blockDim.x + threadIdx.x; i < NN * 64; i += stride) {
        int j = i & 63;
        int v = i >> 6;
        float mean = sums[j] * invN;
        float var  = sums[64 + j] * invN - mean * mean;
        float y = dinv[v] * b2f(ACCb[i]) + blast[j];
        out[i] = (y - mean) * rsqrtf(var + BN_EPS) * gamma[j] + beta[j];
    }
}

// ---------------------------------------------------------------------------
extern "C" void kernel_launch(void* const* d_in, const int* in_sizes, int n_in,
                              void* d_out, int out_size, void* d_ws, size_t ws_size,
                              hipStream_t stream) {
    const float* x     = (const float*)d_in[0];
    const int*   ei    = (const int*)d_in[1];
    const float* Ws    = (const float*)d_in[2];
    const float* bs    = (const float*)d_in[3];
    const float* gamma = (const float*)d_in[4];
    const float* beta  = (const float*)d_in[5];
    float* out = (float*)d_out;

    char* ws = (char*)d_ws;
    size_t off = 0;
    unsigned short* ACCb = (unsigned short*)(ws + off); off += (size_t)NN * 64 * 2;
    unsigned short* Gb   = (unsigned short*)(ws + off); off += (size_t)NN * 64 * 2;
    float* dinv    = (float*)(ws + off); off += (size_t)NN * 4;
    float* sums    = (float*)(ws + off); off += 128 * 4;
    float* c0      = (float*)(ws + off); off += 128 * 4;
    int*   cursor  = (int*)(ws + off);   off += (size_t)NN * 4;
    int*   csr_src = (int*)(ws + off);   off += (size_t)NN * SLOT * 4;

    hipMemsetAsync(cursor, 0, NN * sizeof(int), stream);
    hipMemsetAsync(sums, 0, 128 * sizeof(float), stream);

    // --- slot-CSR build: one bucketed placement pass, no deg/scan kernels ---
    place_part<<<NBUCK * NCHUNK, 256, 0, stream>>>(ei, cursor, csr_src);
    dinv_kernel<<<(NN + 255) / 256, 256, 0, stream>>>(cursor, dinv);
    c0_kernel<<<1, 128, 0, stream>>>(Ws, bs, c0);

    // --- 3 GCN layers ---
    gemm_mfma<1><<<1563, 256, 0, stream>>>(x, Ws, dinv, nullptr, Gb);
    gather_b<<<6144, 256, 0, stream>>>(cursor, csr_src, Gb, ACCb);
    for (int l = 1; l < 3; ++l) {
        gemm_mfma<0><<<1563, 256, 0, stream>>>(ACCb, Ws + (size_t)l * 4096, dinv,
                                               c0 + (l - 1) * 64, Gb);
        gather_b<<<6144, 256, 0, stream>>>(cursor, csr_src, Gb, ACCb);
    }

    // --- BatchNorm over nodes ---
    bn_stats<<<2048, 256, 0, stream>>>(ACCb, dinv, bs + 128, sums);
    bn_apply<<<2048, 256, 0, stream>>>(ACCb, dinv, bs + 128, sums, gamma, beta, out);
}

// Round 8
// 380.738 us; speedup vs baseline: 4.9800x; 1.0851x over previous
//
#include <hip/hip_runtime.h>

#define NN      100000
#define NUSERS  50000
#define NE      1250000
#define DIM     64
#define BN_EPS  1e-5f
#define NBUCK   8       // one bucket per XCD; csr region 2MB + cursor 50KB fits L2
#define NCHUNK  320     // blocks per bucket (grid 2560)
#define SLOT    40      // fixed CSR slots per node (max expected degree ~30)

typedef __attribute__((ext_vector_type(8))) short s16x8;
typedef __attribute__((ext_vector_type(4))) float f32x4;

__device__ __forceinline__ short f2b(float f) {  // fp32 -> bf16 RNE
    unsigned u = __builtin_bit_cast(unsigned, f);
    u = (u + 0x7fffu + ((u >> 16) & 1u)) >> 16;
    return (short)u;
}
__device__ __forceinline__ float b2f(unsigned short s) {
    unsigned u = ((unsigned)s) << 16;
    return __builtin_bit_cast(float, u);
}

// ---------------------------------------------------------------------------
// Slot-CSR placement, 8-bucket XCD-partitioned: csr[d*SLOT + cursor[d]++] = s.
// cursor doubles as the degree count. Plain stores (L2 write-back coalesces
// within the bucket's XCD-resident region); nt loads for the ei stream.
__global__ __launch_bounds__(256) void place_part(const int* __restrict__ ei,
                                                  int* __restrict__ cursor,
                                                  int* __restrict__ csr_src) {
    __shared__ int Qd[4][128];
    __shared__ int Qs[4][128];
    int lane = threadIdx.x & 63, wave = threadIdx.x >> 6;
    int B = blockIdx.x & (NBUCK - 1);
    int gw = (blockIdx.x >> 3) * 4 + wave;
    const int NW  = NCHUNK * 4;
    const int per = (NE + NW - 1) / NW;
    int e0 = gw * per;
    int e1 = e0 + per; if (e1 > NE) e1 = NE;
    int qn = 0;
    for (int e = e0 + lane; e - lane < e1; e += 64) {
        bool keep = false; int d = 0, s = 0;
        if (e < e1) {
            d = __builtin_nontemporal_load(&ei[NE + e]);
            keep = ((d / 12500) == B);
            if (keep) s = __builtin_nontemporal_load(&ei[e]);
        }
        unsigned long long m = __ballot(keep);
        if (keep) {
            int rank = __popcll(m & ((1ull << lane) - 1ull));
            Qd[wave][qn + rank] = d;
            Qs[wave][qn + rank] = s;
        }
        qn += __popcll(m);
        if (qn >= 64) {
            int dd = Qd[wave][lane];
            int ss = Qs[wave][lane];
            int pos = atomicAdd(&cursor[dd], 1);
            if (pos < SLOT) csr_src[dd * SLOT + pos] = ss;
            qn -= 64;
            int mvd = (lane < qn) ? Qd[wave][64 + lane] : 0;
            int mvs = (lane < qn) ? Qs[wave][64 + lane] : 0;
            if (lane < qn) { Qd[wave][lane] = mvd; Qs[wave][lane] = mvs; }
        }
    }
    if (lane < qn) {
        int dd = Qd[wave][lane];
        int pos = atomicAdd(&cursor[dd], 1);
        if (pos < SLOT) csr_src[dd * SLOT + pos] = Qs[wave][lane];
    }
}

// dinv[v] = rsqrt(deg[v] + 1)   (+1 = self-loop); cursor holds true degree
__global__ __launch_bounds__(256) void dinv_kernel(const int* __restrict__ cursor,
                                                   float* __restrict__ dinv) {
    int v = blockIdx.x * blockDim.x + threadIdx.x;
    if (v < NN) dinv[v] = rsqrtf((float)cursor[v] + 1.0f);
}

// ---------------------------------------------------------------------------
// c0[l][j] = sum_k bs[l][k] * Ws[l+1][j][k]   (bias-fold constants, layers 1,2)
__global__ __launch_bounds__(128) void c0_kernel(const float* __restrict__ Ws,
                                                 const float* __restrict__ bs,
                                                 float* __restrict__ c0) {
    int t = threadIdx.x;
    if (t < 128) {
        int l = t >> 6, j = t & 63;
        const float* Wl = Ws + (size_t)(l + 1) * 4096;
        const float* bl = bs + l * 64;
        float s = 0.0f;
        for (int k = 0; k < 64; ++k) s += bl[k] * Wl[j * 64 + k];
        c0[t] = s;
    }
}

// ---------------------------------------------------------------------------
// bf16 MFMA transform: Gb = bf16(scale * (A @ W^T) + dv*c0)  (unchanged)
template <int L0>
__global__ __launch_bounds__(256) void gemm_mfma(const void* __restrict__ Xin,
                                                 const float* __restrict__ W,
                                                 const float* __restrict__ dinv,
                                                 const float* __restrict__ c0,
                                                 unsigned short* __restrict__ Gb) {
    int lane = threadIdx.x & 63;
    int n16 = lane & 15, quad = lane >> 4;

    s16x8 bfrag[4][2];
#pragma unroll
    for (int t = 0; t < 4; ++t)
#pragma unroll
        for (int c = 0; c < 2; ++c) {
            const float4* wp = (const float4*)(W + (t * 16 + n16) * 64 + c * 32 + quad * 8);
            float4 w0 = wp[0], w1 = wp[1];
            s16x8 f;
            f[0] = f2b(w0.x); f[1] = f2b(w0.y); f[2] = f2b(w0.z); f[3] = f2b(w0.w);
            f[4] = f2b(w1.x); f[5] = f2b(w1.y); f[6] = f2b(w1.z); f[7] = f2b(w1.w);
            bfrag[t][c] = f;
        }

    int wid = (blockIdx.x * blockDim.x + threadIdx.x) >> 6;
    int nw  = (gridDim.x * blockDim.x) >> 6;
    for (int tile = wid; tile < NN / 16; tile += nw) {
        int r0 = tile * 16;
        int m  = r0 + n16;
        s16x8 a[2];
#pragma unroll
        for (int c = 0; c < 2; ++c) {
            if (L0) {
                const float4* xp = (const float4*)((const float*)Xin + (size_t)m * 64 + c * 32 + quad * 8);
                float4 x0 = xp[0], x1 = xp[1];
                s16x8 f;
                f[0] = f2b(x0.x); f[1] = f2b(x0.y); f[2] = f2b(x0.z); f[3] = f2b(x0.w);
                f[4] = f2b(x1.x); f[5] = f2b(x1.y); f[6] = f2b(x1.z); f[7] = f2b(x1.w);
                a[c] = f;
            } else {
                a[c] = *(const s16x8*)((const unsigned short*)Xin + (size_t)m * 64 + c * 32 + quad * 8);
            }
        }
        f32x4 acc[4] = {{0,0,0,0},{0,0,0,0},{0,0,0,0},{0,0,0,0}};
#pragma unroll
        for (int c = 0; c < 2; ++c)
#pragma unroll
            for (int t = 0; t < 4; ++t)
                acc[t] = __builtin_amdgcn_mfma_f32_16x16x32_bf16(a[c], bfrag[t][c], acc[t], 0, 0, 0);

        float dvr[4];
#pragma unroll
        for (int r = 0; r < 4; ++r) dvr[r] = dinv[r0 + quad * 4 + r];
#pragma unroll
        for (int t = 0; t < 4; ++t) {
            float cc = L0 ? 0.0f : c0[t * 16 + n16];
#pragma unroll
            for (int r = 0; r < 4; ++r) {
                float dv = dvr[r];
                float g  = L0 ? dv * acc[t][r] : dv * dv * acc[t][r] + dv * cc;
                Gb[(size_t)(r0 + quad * 4 + r) * 64 + t * 16 + n16] = (unsigned short)f2b(g);
            }
        }
    }
}

// ---------------------------------------------------------------------------
// Pair-gather over slot-CSR: each wave processes TWO dst rows concurrently
// (8 independent row loads in flight vs 4). lane = 16*g + c; group g loads the
// 8B chunk (cols 4c..4c+3) of a neighbor; deg <= SLOT < 64 so one 64-wide
// index window covers every row.
__global__ __launch_bounds__(256) void gather_b(const int* __restrict__ cursor,
                                                const int* __restrict__ csr_src,
                                                const unsigned short* __restrict__ Gb,
                                                unsigned short* __restrict__ ACCb) {
    int lane = threadIdx.x & 63;
    int c = lane & 15, g = lane >> 4;
    int wid  = (blockIdx.x * blockDim.x + threadIdx.x) >> 6;
    int nw   = (gridDim.x * blockDim.x) >> 6;
    for (int v = wid * 2; v < NN; v += nw * 2) {
        int w = v + 1;  // NN even -> always valid
        int n0 = cursor[v]; if (n0 > SLOT) n0 = SLOT;
        int n1 = cursor[w]; if (n1 > SLOT) n1 = SLOT;
        float m0 = (g == 0) ? 1.0f : 0.0f;
        float a0x, a0y, a0z, a0w, a1x, a1y, a1z, a1w;
        {
            ushort4 s0 = *(const ushort4*)(Gb + (size_t)v * 64 + c * 4);
            ushort4 s1 = *(const ushort4*)(Gb + (size_t)w * 64 + c * 4);
            a0x = m0 * b2f(s0.x); a0y = m0 * b2f(s0.y);
            a0z = m0 * b2f(s0.z); a0w = m0 * b2f(s0.w);
            a1x = m0 * b2f(s1.x); a1y = m0 * b2f(s1.y);
            a1z = m0 * b2f(s1.z); a1w = m0 * b2f(s1.w);
        }
        int idx0 = (lane < n0) ? csr_src[v * SLOT + lane] : 0;
        int idx1 = (lane < n1) ? csr_src[w * SLOT + lane] : 0;
        int nmax = (n0 > n1) ? n0 : n1;
        for (int t = 0; t < nmax; t += 16) {
            ushort4 val0[4], val1[4];
            float msk0[4], msk1[4];
#pragma unroll
            for (int u = 0; u < 4; ++u) {
                int nb = t + u * 4 + g;
                int s0 = __shfl(idx0, nb & 63, 64);
                int s1 = __shfl(idx1, nb & 63, 64);
                bool ok0 = nb < n0, ok1 = nb < n1;
                msk0[u] = ok0 ? 1.0f : 0.0f;
                msk1[u] = ok1 ? 1.0f : 0.0f;
                val0[u] = *(const ushort4*)(Gb + (size_t)(ok0 ? s0 : v) * 64 + c * 4);
                val1[u] = *(const ushort4*)(Gb + (size_t)(ok1 ? s1 : w) * 64 + c * 4);
            }
#pragma unroll
            for (int u = 0; u < 4; ++u) {
                a0x = fmaf(msk0[u], b2f(val0[u].x), a0x);
                a0y = fmaf(msk0[u], b2f(val0[u].y), a0y);
                a0z = fmaf(msk0[u], b2f(val0[u].z), a0z);
                a0w = fmaf(msk0[u], b2f(val0[u].w), a0w);
                a1x = fmaf(msk1[u], b2f(val1[u].x), a1x);
                a1y = fmaf(msk1[u], b2f(val1[u].y), a1y);
                a1z = fmaf(msk1[u], b2f(val1[u].z), a1z);
                a1w = fmaf(msk1[u], b2f(val1[u].w), a1w);
            }
        }
#pragma unroll
        for (int off = 16; off < 64; off <<= 1) {
            a0x += __shfl_xor(a0x, off, 64); a0y += __shfl_xor(a0y, off, 64);
            a0z += __shfl_xor(a0z, off, 64); a0w += __shfl_xor(a0w, off, 64);
            a1x += __shfl_xor(a1x, off, 64); a1y += __shfl_xor(a1y, off, 64);
            a1z += __shfl_xor(a1z, off, 64); a1w += __shfl_xor(a1w, off, 64);
        }
        if (g == 0) {
            ushort4 o0, o1;
            o0.x = (unsigned short)f2b(a0x); o0.y = (unsigned short)f2b(a0y);
            o0.z = (unsigned short)f2b(a0z); o0.w = (unsigned short)f2b(a0w);
            o1.x = (unsigned short)f2b(a1x); o1.y = (unsigned short)f2b(a1y);
            o1.z = (unsigned short)f2b(a1z); o1.w = (unsigned short)f2b(a1w);
            *(ushort4*)(ACCb + (size_t)v * 64 + c * 4) = o0;
            *(ushort4*)(ACCb + (size_t)w * 64 + c * 4) = o1;
        }
    }
}

// ---------------------------------------------------------------------------
__global__ __launch_bounds__(256) void bn_stats(const unsigned short* __restrict__ ACCb,
                                                const float* __restrict__ dinv,
                                                const float* __restrict__ blast,
                                                float* __restrict__ sums) {
    int j = threadIdx.x & 63;
    float b = blast[j];
    int wid = (blockIdx.x * blockDim.x + threadIdx.x) >> 6;
    int nw  = (gridDim.x * blockDim.x) >> 6;
    float s = 0.0f, s2 = 0.0f;
    for (int v = wid; v < NN; v += nw) {
        float y = dinv[v] * b2f(ACCb[(size_t)v * 64 + j]) + b;
        s += y;
        s2 += y * y;
    }
    __shared__ float ls[256], ls2[256];
    ls[threadIdx.x] = s;
    ls2[threadIdx.x] = s2;
    __syncthreads();
    if (threadIdx.x < 64) {
        s  = ls[threadIdx.x] + ls[threadIdx.x + 64] + ls[threadIdx.x + 128] + ls[threadIdx.x + 192];
        s2 = ls2[threadIdx.x] + ls2[threadIdx.x + 64] + ls2[threadIdx.x + 128] + ls2[threadIdx.x + 192];
        atomicAdd(&sums[j], s);
        atomicAdd(&sums[64 + j], s2);
    }
}

__global__ __launch_bounds__(256) void bn_apply(const unsigned short* __restrict__ ACCb,
                                                const float* __restrict__ dinv,
                                                const float* __restrict__ blast,
                                                const float* __restrict__ sums,
                                                const float* __restrict__ gamma,
                                                const float* __restrict__ beta,
                                                float* __restrict__ out) {
    const float invN = 1.0f / (float)NN;
    int stride = gridDim.x * blockDim.x;
    for (int i = blockIdx.x * blockDim.x + threadIdx.x; i < NN * 64; i += stride) {
        int j = i & 63;
        int v = i >> 6;
        float mean = sums[j] * invN;
        float var  = sums[64 + j] * invN - mean * mean;
        float y = dinv[v] * b2f(ACCb[i]) + blast[j];
        out[i] = (y - mean) * rsqrtf(var + BN_EPS) * gamma[j] + beta[j];
    }
}

// ---------------------------------------------------------------------------
extern "C" void kernel_launch(void* const* d_in, const int* in_sizes, int n_in,
                              void* d_out, int out_size, void* d_ws, size_t ws_size,
                              hipStream_t stream) {
    const float* x     = (const float*)d_in[0];
    const int*   ei    = (const int*)d_in[1];
    const float* Ws    = (const float*)d_in[2];
    const float* bs    = (const float*)d_in[3];
    const float* gamma = (const float*)d_in[4];
    const float* beta  = (const float*)d_in[5];
    float* out = (float*)d_out;

    char* ws = (char*)d_ws;
    size_t off = 0;
    unsigned short* ACCb = (unsigned short*)(ws + off); off += (size_t)NN * 64 * 2;
    unsigned short* Gb   = (unsigned short*)(ws + off); off += (size_t)NN * 64 * 2;
    float* dinv    = (float*)(ws + off); off += (size_t)NN * 4;
    float* sums    = (float*)(ws + off); off += 128 * 4;
    float* c0      = (float*)(ws + off); off += 128 * 4;
    int*   cursor  = (int*)(ws + off);   off += (size_t)NN * 4;
    int*   csr_src = (int*)(ws + off);   off += (size_t)NN * SLOT * 4;

    hipMemsetAsync(cursor, 0, NN * sizeof(int), stream);
    hipMemsetAsync(sums, 0, 128 * sizeof(float), stream);

    // --- slot-CSR build: one bucketed placement pass ---
    place_part<<<NBUCK * NCHUNK, 256, 0, stream>>>(ei, cursor, csr_src);
    dinv_kernel<<<(NN + 255) / 256, 256, 0, stream>>>(cursor, dinv);
    c0_kernel<<<1, 128, 0, stream>>>(Ws, bs, c0);

    // --- 3 GCN layers ---
    gemm_mfma<1><<<1563, 256, 0, stream>>>(x, Ws, dinv, nullptr, Gb);
    gather_b<<<3072, 256, 0, stream>>>(cursor, csr_src, Gb, ACCb);
    for (int l = 1; l < 3; ++l) {
        gemm_mfma<0><<<1563, 256, 0, stream>>>(ACCb, Ws + (size_t)l * 4096, dinv,
                                               c0 + (l - 1) * 64, Gb);
        gather_b<<<3072, 256, 0, stream>>>(cursor, csr_src, Gb, ACCb);
    }

    // --- BatchNorm over nodes ---
    bn_stats<<<2048, 256, 0, stream>>>(ACCb, dinv, bs + 128, sums);
    bn_apply<<<2048, 256, 0, stream>>>(ACCb, dinv, bs + 128, sums, gamma, beta, out);
}